// Round 1
// baseline (2979.184 us; speedup 1.0000x reference)
//
#include <hip/hip_runtime.h>
#include <hip/hip_bf16.h>

// HeteroRGCN on MI355X — dead-code-eliminated dataflow:
//   out = (mean_c2t(g_c) + mean_d2t(g_d)) @ W_out + b_out
//   g_c = lrelu(mean_t2c(features@W1[1]+b1[1])) @ W2[0] + b2[0]
//   g_d = lrelu(mean_t2d(features@W1[3]+b1[3])) @ W2[2] + b2[2]
// emb_card/emb_device/W1[0]/W1[2]/layer-2 h_c,h_d are dead.

#define NT 500000
#define NC 200000
#define ND 100000
#define NE 1000000
#define H  64

// ---------------- degree counting ----------------
__global__ void deg_count(const int* __restrict__ dst, float* __restrict__ deg, int n) {
    int i = blockIdx.x * blockDim.x + threadIdx.x;
    if (i < n) atomicAdd(&deg[dst[i]], 1.0f);
}

__global__ void invert_deg(float* __restrict__ deg, int n) {
    int i = blockIdx.x * blockDim.x + threadIdx.x;
    if (i < n) deg[i] = 1.0f / fmaxf(deg[i], 1.0f);
}

// ---------------- layer-1 scatter with on-the-fly 64x64 transform ----------------
// wave per edge: lane j computes y_j = b_j + sum_k x_k * W[k][j], then
// atomicAdd acc[dst*64+j] += y_j * invdeg[dst]   (scaled atomic == mean)
__global__ void scatter_xform(const float* __restrict__ X,
                              const int* __restrict__ src, const int* __restrict__ dst,
                              const float* __restrict__ W, const float* __restrict__ b,
                              const float* __restrict__ invdeg, float* __restrict__ acc,
                              int nE) {
    __shared__ float Wl[H * H];
    __shared__ float bl[H];
    int t = threadIdx.x;
    for (int i = t; i < H * H; i += 256) Wl[i] = W[i];
    if (t < H) bl[t] = b[t];
    __syncthreads();

    int lane = t & 63;
    int wid  = t >> 6;
    int e = blockIdx.x * 4 + wid;
    if (e >= nE) return;

    int s = src[e];
    int d = dst[e];
    float x = X[(long)s * H + lane];      // coalesced 256B row gather
    float y = bl[lane];
#pragma unroll
    for (int k = 0; k < H; ++k) {
        float xk = __shfl(x, k);          // broadcast of lane k
        y = fmaf(xk, Wl[k * H + lane], y);
    }
    float sc = invdeg[d];
    atomicAdd(&acc[(long)d * H + lane], y * sc);
}

// ---------------- node update: mean already applied; lrelu; @W2 (+b2) in-place ----------------
__global__ void node_update(float* __restrict__ A,
                            const float* __restrict__ W, const float* __restrict__ b,
                            int n) {
    __shared__ float Wl[H * H];
    __shared__ float bl[H];
    int t = threadIdx.x;
    for (int i = t; i < H * H; i += 256) Wl[i] = W[i];
    if (t < H) bl[t] = b[t];
    __syncthreads();

    int lane = t & 63;
    int wid  = t >> 6;
    int node = blockIdx.x * 4 + wid;
    if (node >= n) return;

    float h = A[(long)node * H + lane];
    h = (h > 0.0f) ? h : 0.01f * h;       // leaky_relu 0.01
    float y = bl[lane];
#pragma unroll
    for (int k = 0; k < H; ++k) {
        float hk = __shfl(h, k);
        y = fmaf(hk, Wl[k * H + lane], y);
    }
    A[(long)node * H + lane] = y;         // in-place safe: row owned by this wave
}

// ---------------- layer-2 scatter (no transform) ----------------
__global__ void scatter_plain(const float* __restrict__ G,
                              const int* __restrict__ src, const int* __restrict__ dst,
                              const float* __restrict__ invdeg, float* __restrict__ acc,
                              int nE) {
    int t = threadIdx.x;
    int lane = t & 63;
    int wid  = t >> 6;
    int e = blockIdx.x * 4 + wid;
    if (e >= nE) return;
    int s = src[e];
    int d = dst[e];
    float g = G[(long)s * H + lane];
    atomicAdd(&acc[(long)d * H + lane], g * invdeg[d]);
}

// ---------------- output: out = acc_t @ W_out + b_out ----------------
__global__ void out_proj(const float* __restrict__ A,
                         const float* __restrict__ Wout, const float* __restrict__ bout,
                         float* __restrict__ out, int n) {
    int t = threadIdx.x;
    int lane = t & 63;
    int wid  = t >> 6;
    int node = blockIdx.x * 4 + wid;
    if (node >= n) return;
    float h = A[(long)node * H + lane];
    float p0 = h * Wout[lane * 2 + 0];
    float p1 = h * Wout[lane * 2 + 1];
#pragma unroll
    for (int off = 32; off > 0; off >>= 1) {
        p0 += __shfl_down(p0, off);
        p1 += __shfl_down(p1, off);
    }
    if (lane == 0) {
        out[(long)node * 2 + 0] = p0 + bout[0];
        out[(long)node * 2 + 1] = p1 + bout[1];
    }
}

extern "C" void kernel_launch(void* const* d_in, const int* in_sizes, int n_in,
                              void* d_out, int out_size, void* d_ws, size_t ws_size,
                              hipStream_t stream) {
    const float* features = (const float*)d_in[0];
    // d_in[1] emb_card, d_in[2] emb_device: dead
    const float* W1 = (const float*)d_in[3];
    const float* b1 = (const float*)d_in[4];
    const float* W2 = (const float*)d_in[5];
    const float* b2 = (const float*)d_in[6];
    const float* W_out = (const float*)d_in[7];
    const float* b_out = (const float*)d_in[8];
    const int* src_c2t = (const int*)d_in[9];
    const int* dst_c2t = (const int*)d_in[10];
    const int* src_t2c = (const int*)d_in[11];
    const int* dst_t2c = (const int*)d_in[12];
    const int* src_d2t = (const int*)d_in[13];
    const int* dst_d2t = (const int*)d_in[14];
    const int* src_t2d = (const int*)d_in[15];
    const int* dst_t2d = (const int*)d_in[16];
    float* out = (float*)d_out;

    // workspace carve (floats)
    float* ws = (float*)d_ws;
    float* acc_t = ws;                        // NT*64 = 32,000,000
    float* acc_c = acc_t + (long)NT * H;      // NC*64 = 12,800,000
    float* acc_d = acc_c + (long)NC * H;      // ND*64 =  6,400,000
    float* inv_c2t = acc_d + (long)ND * H;    // NT = 500,000 (per-target deg of c2t)
    float* inv_d2t = inv_c2t + NT;            // NT = 500,000
    float* inv_t2c = inv_d2t + NT;            // NC = 200,000
    float* inv_t2d = inv_t2c + NC;            // ND = 100,000
    size_t total_floats = (size_t)NT * H + (size_t)NC * H + (size_t)ND * H
                        + NT + NT + NC + ND;  // 52,500,000

    // zero accumulators + degree arrays (fresh every call — harness poisons ws)
    hipMemsetAsync(d_ws, 0, total_floats * sizeof(float), stream);

    const int B = 256;
    int gE = (NE + B - 1) / B;
    // degrees
    deg_count<<<gE, B, 0, stream>>>(dst_c2t, inv_c2t, NE);
    deg_count<<<gE, B, 0, stream>>>(dst_d2t, inv_d2t, NE);
    deg_count<<<gE, B, 0, stream>>>(dst_t2c, inv_t2c, NE);
    deg_count<<<gE, B, 0, stream>>>(dst_t2d, inv_t2d, NE);
    int nDeg = NT + NT + NC + ND;
    invert_deg<<<(nDeg + B - 1) / B, B, 0, stream>>>(inv_c2t, nDeg);

    // layer 1: features -> acc_c (W1[1],b1[1]), features -> acc_d (W1[3],b1[3])
    int gW = (NE + 3) / 4;  // 4 edges per 256-thread block
    scatter_xform<<<gW, B, 0, stream>>>(features, src_t2c, dst_t2c,
                                        W1 + 1 * H * H, b1 + 1 * H,
                                        inv_t2c, acc_c, NE);
    scatter_xform<<<gW, B, 0, stream>>>(features, src_t2d, dst_t2d,
                                        W1 + 3 * H * H, b1 + 3 * H,
                                        inv_t2d, acc_d, NE);

    // node update: lrelu + @W2 (in place)
    node_update<<<(NC + 3) / 4, B, 0, stream>>>(acc_c, W2 + 0 * H * H, b2 + 0 * H, NC);
    node_update<<<(ND + 3) / 4, B, 0, stream>>>(acc_d, W2 + 2 * H * H, b2 + 2 * H, ND);

    // layer 2: g_c -> acc_t (c2t), g_d -> acc_t (d2t)
    scatter_plain<<<gW, B, 0, stream>>>(acc_c, src_c2t, dst_c2t, inv_c2t, acc_t, NE);
    scatter_plain<<<gW, B, 0, stream>>>(acc_d, src_d2t, dst_d2t, inv_d2t, acc_t, NE);

    // output projection
    out_proj<<<(NT + 3) / 4, B, 0, stream>>>(acc_t, W_out, b_out, out, NT);
}